// Round 1
// baseline (771.077 us; speedup 1.0000x reference)
//
#include <hip/hip_runtime.h>

// ---------------- CSR build ----------------

__global__ __launch_bounds__(256) void k_count(const int* __restrict__ col, int* __restrict__ cnt, int E) {
    int e = blockIdx.x * 256 + threadIdx.x;
    if (e < E) atomicAdd(&cnt[col[e]], 1);
}

__global__ __launch_bounds__(256) void k_dinv(const int* __restrict__ cnt, float* __restrict__ dinv, int N) {
    int n = blockIdx.x * 256 + threadIdx.x;
    if (n < N) dinv[n] = 1.0f / sqrtf((float)(cnt[n] + 1));  // +1 self loop; deg>=1 always
}

__global__ __launch_bounds__(256) void k_tile_reduce(const int* __restrict__ cnt, int* __restrict__ sums, int N) {
    __shared__ int red[256];
    int base = blockIdx.x * 1024;
    int s = 0;
    for (int i = threadIdx.x; i < 1024; i += 256) {
        int idx = base + i;
        if (idx < N) s += cnt[idx];
    }
    red[threadIdx.x] = s;
    __syncthreads();
    for (int off = 128; off > 0; off >>= 1) {
        if (threadIdx.x < off) red[threadIdx.x] += red[threadIdx.x + off];
        __syncthreads();
    }
    if (threadIdx.x == 0) sums[blockIdx.x] = red[0];
}

__global__ void k_scan_sums(const int* __restrict__ sums, int* __restrict__ toff, int NT,
                            int* __restrict__ colptr, int N) {
    if (threadIdx.x == 0 && blockIdx.x == 0) {
        int run = 0;
        for (int i = 0; i < NT; i++) { toff[i] = run; run += sums[i]; }
        colptr[N] = run;  // == E
    }
}

__global__ __launch_bounds__(256) void k_tile_scan(const int* __restrict__ cnt, const int* __restrict__ toff,
                                                   int* __restrict__ colptr, int* __restrict__ fillptr, int N) {
    __shared__ int ts[256];
    int tid = threadIdx.x;
    int base = blockIdx.x * 1024 + tid * 4;
    int v[4];
#pragma unroll
    for (int j = 0; j < 4; j++) {
        int idx = base + j;
        v[j] = (idx < N) ? cnt[idx] : 0;
    }
    ts[tid] = v[0] + v[1] + v[2] + v[3];
    __syncthreads();
    for (int off = 1; off < 256; off <<= 1) {
        int x = (tid >= off) ? ts[tid - off] : 0;
        __syncthreads();
        ts[tid] += x;
        __syncthreads();
    }
    int run = (tid ? ts[tid - 1] : 0) + toff[blockIdx.x];
#pragma unroll
    for (int j = 0; j < 4; j++) {
        int idx = base + j;
        if (idx < N) { colptr[idx] = run; fillptr[idx] = run; run += v[j]; }
    }
}

__global__ __launch_bounds__(256) void k_fill(const int* __restrict__ row, const int* __restrict__ col,
                                              int* __restrict__ fillptr, int* __restrict__ srcarr, int E) {
    int e = blockIdx.x * 256 + threadIdx.x;
    if (e < E) {
        int c = col[e];
        int pos = atomicAdd(&fillptr[c], 1);
        srcarr[pos] = row[e];
    }
}

// ---------------- GEMM: A = (H @ W) * dinv[row] ----------------
// 64 rows/block, 256 threads, W staged in LDS (64KB), 4x8 register tile/thread.

__global__ __launch_bounds__(256) void k_gemm_scale(const float* __restrict__ H, const float* __restrict__ W,
                                                    const float* __restrict__ dinv, float* __restrict__ A, int N) {
    __shared__ float4 wl4[4096];  // 128x128 f32 = 64KB
    int tid = threadIdx.x;
    const float4* __restrict__ W4 = (const float4*)W;
#pragma unroll
    for (int i = 0; i < 16; i++) wl4[i * 256 + tid] = W4[i * 256 + tid];
    __syncthreads();

    int tc = tid & 15;   // col group: cols tc*8 .. tc*8+7
    int tr = tid >> 4;   // row group: 4 rows
    int rbase = blockIdx.x * 64 + tr * 4;

    const float4* __restrict__ H4 = (const float4*)H;
    float acc[4][8] = {};
    int r[4];
#pragma unroll
    for (int j = 0; j < 4; j++) {
        int rr = rbase + j;
        r[j] = (rr < N) ? rr : (N - 1);
    }

#pragma unroll 4
    for (int k4 = 0; k4 < 32; k4++) {
        union { float4 v; float f[4]; } hu[4];
#pragma unroll
        for (int j = 0; j < 4; j++) hu[j].v = H4[r[j] * 32 + k4];
#pragma unroll
        for (int kk = 0; kk < 4; kk++) {
            float4 w0 = wl4[(k4 * 4 + kk) * 32 + tc * 2];
            float4 w1 = wl4[(k4 * 4 + kk) * 32 + tc * 2 + 1];
#pragma unroll
            for (int j = 0; j < 4; j++) {
                float h = hu[j].f[kk];
                acc[j][0] = fmaf(h, w0.x, acc[j][0]);
                acc[j][1] = fmaf(h, w0.y, acc[j][1]);
                acc[j][2] = fmaf(h, w0.z, acc[j][2]);
                acc[j][3] = fmaf(h, w0.w, acc[j][3]);
                acc[j][4] = fmaf(h, w1.x, acc[j][4]);
                acc[j][5] = fmaf(h, w1.y, acc[j][5]);
                acc[j][6] = fmaf(h, w1.z, acc[j][6]);
                acc[j][7] = fmaf(h, w1.w, acc[j][7]);
            }
        }
    }

    float4* __restrict__ A4 = (float4*)A;
#pragma unroll
    for (int j = 0; j < 4; j++) {
        int rr = rbase + j;
        if (rr < N) {
            float dn = dinv[rr];
            A4[rr * 32 + tc * 2]     = make_float4(acc[j][0] * dn, acc[j][1] * dn, acc[j][2] * dn, acc[j][3] * dn);
            A4[rr * 32 + tc * 2 + 1] = make_float4(acc[j][4] * dn, acc[j][5] * dn, acc[j][6] * dn, acc[j][7] * dn);
        }
    }
}

// ---------------- Aggregation: B[n] = relu(dinv[n]*(sum_e A[src_e] + A[n]) + bias) ----------------
// One wave (64 lanes) per node; lane covers 2 feature columns (float2).

__global__ __launch_bounds__(256) void k_agg(const float* __restrict__ A, const int* __restrict__ colptr,
                                             const int* __restrict__ srcarr, const float* __restrict__ dinv,
                                             const float* __restrict__ bias, float* __restrict__ Bout, int N) {
    int wid = blockIdx.x * 4 + (threadIdx.x >> 6);
    int lane = threadIdx.x & 63;
    if (wid >= N) return;
    const float2* __restrict__ A2 = (const float2*)A;
    int s = colptr[wid], e = colptr[wid + 1];
    float2 self = A2[wid * 64 + lane];
    float ax = self.x, ay = self.y;
    int i = s;
    for (; i + 2 <= e; i += 2) {
        int s0 = srcarr[i], s1 = srcarr[i + 1];
        float2 v0 = A2[s0 * 64 + lane];
        float2 v1 = A2[s1 * 64 + lane];
        ax += v0.x + v1.x;
        ay += v0.y + v1.y;
    }
    if (i < e) {
        int s0 = srcarr[i];
        float2 v0 = A2[s0 * 64 + lane];
        ax += v0.x;
        ay += v0.y;
    }
    float dn = dinv[wid];
    float bx = bias[2 * lane], by = bias[2 * lane + 1];
    float ox = fmaxf(fmaf(ax, dn, bx), 0.f);
    float oy = fmaxf(fmaf(ay, dn, by), 0.f);
    ((float2*)Bout)[wid * 64 + lane] = make_float2(ox, oy);
}

// ---------------- Pool (mean per graph, sorted batch) + head ----------------

__global__ __launch_bounds__(512) void k_pool(const float* __restrict__ B, const int* __restrict__ batch,
                                              const float* __restrict__ Wl, const float* __restrict__ bl,
                                              float* __restrict__ out, int N) {
    int g = blockIdx.x;
    int tid = threadIdx.x;
    int k = tid & 127, h = tid >> 7;  // h in 0..3
    __shared__ int se[2];
    __shared__ float red[4][128];
    if (tid < 2) {
        int target = g + tid;  // lower_bound(batch, target)
        int lo = 0, hi = N;
        while (lo < hi) {
            int mid = (lo + hi) >> 1;
            if (batch[mid] < target) lo = mid + 1; else hi = mid;
        }
        se[tid] = lo;
    }
    __syncthreads();
    int start = se[0], end = se[1];
    float s = 0.f;
    for (int n = start + h; n < end; n += 4) s += B[n * 128 + k];
    red[h][k] = s;
    __syncthreads();
    if (h == 0) {
        float tot = red[0][k] + red[1][k] + red[2][k] + red[3][k];
        int cg = end - start;
        red[0][k] = tot / (float)(cg > 1 ? cg : 1);
    }
    __syncthreads();
    if (tid < 10) {
        float o = bl[tid];
        for (int j = 0; j < 128; j++) o = fmaf(red[0][j], Wl[j * 10 + tid], o);
        out[g * 10 + tid] = o;
    }
}

// ---------------- launch ----------------

extern "C" void kernel_launch(void* const* d_in, const int* in_sizes, int n_in,
                              void* d_out, int out_size, void* d_ws, size_t ws_size,
                              hipStream_t stream) {
    const float* x  = (const float*)d_in[0];
    const int* eidx = (const int*)d_in[1];
    const int* batch = (const int*)d_in[2];
    const float* W0 = (const float*)d_in[3];
    const float* b0 = (const float*)d_in[4];
    const float* W1 = (const float*)d_in[5];
    const float* b1 = (const float*)d_in[6];
    const float* W2 = (const float*)d_in[7];
    const float* b2 = (const float*)d_in[8];
    const float* Wl = (const float*)d_in[9];
    const float* bl = (const float*)d_in[10];

    int N = in_sizes[0] / 128;
    int E = in_sizes[1] / 2;
    int G = out_size / 10;
    const int* row = eidx;      // edge_index[0] = source
    const int* col = eidx + E;  // edge_index[1] = target

    char* w = (char*)d_ws;
    auto carve = [&](size_t bytes) -> void* {
        void* p = (void*)w;
        w += (bytes + 511) & ~(size_t)511;
        return p;
    };
    float* A      = (float*)carve((size_t)N * 128 * 4);
    float* Bb     = (float*)carve((size_t)N * 128 * 4);
    int*   cnt    = (int*)carve((size_t)N * 4);
    float* dinv   = (float*)carve((size_t)N * 4);
    int*   colptr = (int*)carve((size_t)(N + 1) * 4);
    int*   fillptr= (int*)carve((size_t)(N + 1) * 4);
    int*   srcarr = (int*)carve((size_t)E * 4);
    int NT = (N + 1023) / 1024;
    int*   sums   = (int*)carve((size_t)NT * 4);
    int*   toff   = (int*)carve((size_t)NT * 4);

    // CSR build (re-done every call; ws is not re-poisoned but we overwrite everything we read)
    hipMemsetAsync(cnt, 0, (size_t)N * 4, stream);
    k_count<<<(E + 255) / 256, 256, 0, stream>>>(col, cnt, E);
    k_dinv<<<(N + 255) / 256, 256, 0, stream>>>(cnt, dinv, N);
    k_tile_reduce<<<NT, 256, 0, stream>>>(cnt, sums, N);
    k_scan_sums<<<1, 64, 0, stream>>>(sums, toff, NT, colptr, N);
    k_tile_scan<<<NT, 256, 0, stream>>>(cnt, toff, colptr, fillptr, N);
    k_fill<<<(E + 255) / 256, 256, 0, stream>>>(row, col, fillptr, srcarr, E);

    int gb = (N + 63) / 64;
    int ab = (N + 3) / 4;
    // layer 1
    k_gemm_scale<<<gb, 256, 0, stream>>>(x, W0, dinv, A, N);
    k_agg<<<ab, 256, 0, stream>>>(A, colptr, srcarr, dinv, b0, Bb, N);
    // layer 2
    k_gemm_scale<<<gb, 256, 0, stream>>>(Bb, W1, dinv, A, N);
    k_agg<<<ab, 256, 0, stream>>>(A, colptr, srcarr, dinv, b1, Bb, N);
    // layer 3
    k_gemm_scale<<<gb, 256, 0, stream>>>(Bb, W2, dinv, A, N);
    k_agg<<<ab, 256, 0, stream>>>(A, colptr, srcarr, dinv, b2, Bb, N);
    // pool + head
    k_pool<<<G, 512, 0, stream>>>(Bb, batch, Wl, bl, (float*)d_out, N);
}

// Round 2
// 681.586 us; speedup vs baseline: 1.1313x; 1.1313x over previous
//
#include <hip/hip_runtime.h>

#define ELL_D 64  // max in-degree slots; Poisson(16) => P(deg>=64) ~ 2e-18/node

// ---------------- ELL build ----------------

__global__ __launch_bounds__(256) void k_fill_ell(const int* __restrict__ row, const int* __restrict__ col,
                                                  int* __restrict__ cnt, int* __restrict__ ell, int E) {
    int e = blockIdx.x * 256 + threadIdx.x;
    if (e < E) {
        int c = col[e];
        int pos = atomicAdd(&cnt[c], 1);
        ell[c * ELL_D + pos] = row[e];
    }
}

__global__ __launch_bounds__(256) void k_dinv(const int* __restrict__ cnt, float* __restrict__ dinv, int N) {
    int n = blockIdx.x * 256 + threadIdx.x;
    if (n < N) dinv[n] = 1.0f / sqrtf((float)(cnt[n] + 1));  // +1 self loop; deg>=1 always
}

// ---------------- GEMM: A = (H @ W) * dinv[row] ----------------
// 64 rows/block, 256 threads, W staged in LDS (64KB), 4x8 register tile/thread.

__global__ __launch_bounds__(256) void k_gemm_scale(const float* __restrict__ H, const float* __restrict__ W,
                                                    const float* __restrict__ dinv, float* __restrict__ A, int N) {
    __shared__ float4 wl4[4096];  // 128x128 f32 = 64KB
    int tid = threadIdx.x;
    const float4* __restrict__ W4 = (const float4*)W;
#pragma unroll
    for (int i = 0; i < 16; i++) wl4[i * 256 + tid] = W4[i * 256 + tid];
    __syncthreads();

    int tc = tid & 15;   // col group: cols tc*8 .. tc*8+7
    int tr = tid >> 4;   // row group: 4 rows
    int rbase = blockIdx.x * 64 + tr * 4;

    const float4* __restrict__ H4 = (const float4*)H;
    float acc[4][8] = {};
    int r[4];
#pragma unroll
    for (int j = 0; j < 4; j++) {
        int rr = rbase + j;
        r[j] = (rr < N) ? rr : (N - 1);
    }

#pragma unroll 4
    for (int k4 = 0; k4 < 32; k4++) {
        union { float4 v; float f[4]; } hu[4];
#pragma unroll
        for (int j = 0; j < 4; j++) hu[j].v = H4[r[j] * 32 + k4];
#pragma unroll
        for (int kk = 0; kk < 4; kk++) {
            float4 w0 = wl4[(k4 * 4 + kk) * 32 + tc * 2];
            float4 w1 = wl4[(k4 * 4 + kk) * 32 + tc * 2 + 1];
#pragma unroll
            for (int j = 0; j < 4; j++) {
                float h = hu[j].f[kk];
                acc[j][0] = fmaf(h, w0.x, acc[j][0]);
                acc[j][1] = fmaf(h, w0.y, acc[j][1]);
                acc[j][2] = fmaf(h, w0.z, acc[j][2]);
                acc[j][3] = fmaf(h, w0.w, acc[j][3]);
                acc[j][4] = fmaf(h, w1.x, acc[j][4]);
                acc[j][5] = fmaf(h, w1.y, acc[j][5]);
                acc[j][6] = fmaf(h, w1.z, acc[j][6]);
                acc[j][7] = fmaf(h, w1.w, acc[j][7]);
            }
        }
    }

    float4* __restrict__ A4 = (float4*)A;
#pragma unroll
    for (int j = 0; j < 4; j++) {
        int rr = rbase + j;
        if (rr < N) {
            float dn = dinv[rr];
            A4[rr * 32 + tc * 2]     = make_float4(acc[j][0] * dn, acc[j][1] * dn, acc[j][2] * dn, acc[j][3] * dn);
            A4[rr * 32 + tc * 2 + 1] = make_float4(acc[j][4] * dn, acc[j][5] * dn, acc[j][6] * dn, acc[j][7] * dn);
        }
    }
}

// ---------------- Aggregation: B[n] = relu(dinv[n]*(sum_e A[src_e] + A[n]) + bias) ----------------
// One wave (64 lanes) per node; lane covers 2 feature columns (float2).
// ELL edge list: 4 edge IDs per int4 load, 4 independent row-gathers in flight.

__global__ __launch_bounds__(256) void k_agg(const float* __restrict__ A, const int* __restrict__ cnt,
                                             const int* __restrict__ ell, const float* __restrict__ dinv,
                                             const float* __restrict__ bias, float* __restrict__ Bout, int N) {
    int wid = blockIdx.x * 4 + (threadIdx.x >> 6);
    int lane = threadIdx.x & 63;
    if (wid >= N) return;
    const float2* __restrict__ A2 = (const float2*)A;
    int deg = cnt[wid];
    const int4* __restrict__ l4 = (const int4*)(ell + wid * ELL_D);

    float2 self = A2[wid * 64 + lane];
    float ax = self.x, ay = self.y;

    int q = 0, nq = deg >> 2;
    for (; q < nq; q++) {
        int4 s = l4[q];
        float2 v0 = A2[s.x * 64 + lane];
        float2 v1 = A2[s.y * 64 + lane];
        float2 v2 = A2[s.z * 64 + lane];
        float2 v3 = A2[s.w * 64 + lane];
        ax += (v0.x + v1.x) + (v2.x + v3.x);
        ay += (v0.y + v1.y) + (v2.y + v3.y);
    }
    const int* __restrict__ lst = (const int*)l4;
    for (int i = nq << 2; i < deg; i++) {
        int s0 = lst[i];
        float2 v = A2[s0 * 64 + lane];
        ax += v.x;
        ay += v.y;
    }

    float dn = dinv[wid];
    float bx = bias[2 * lane], by = bias[2 * lane + 1];
    float ox = fmaxf(fmaf(ax, dn, bx), 0.f);
    float oy = fmaxf(fmaf(ay, dn, by), 0.f);
    ((float2*)Bout)[wid * 64 + lane] = make_float2(ox, oy);
}

// ---------------- Pool (mean per graph, sorted batch) + head ----------------

__global__ __launch_bounds__(512) void k_pool(const float* __restrict__ B, const int* __restrict__ batch,
                                              const float* __restrict__ Wl, const float* __restrict__ bl,
                                              float* __restrict__ out, int N) {
    int g = blockIdx.x;
    int tid = threadIdx.x;
    int k = tid & 127, h = tid >> 7;  // h in 0..3
    __shared__ int se[2];
    __shared__ float red[4][128];
    if (tid < 2) {
        int target = g + tid;  // lower_bound(batch, target)
        int lo = 0, hi = N;
        while (lo < hi) {
            int mid = (lo + hi) >> 1;
            if (batch[mid] < target) lo = mid + 1; else hi = mid;
        }
        se[tid] = lo;
    }
    __syncthreads();
    int start = se[0], end = se[1];
    float s = 0.f;
    for (int n = start + h; n < end; n += 4) s += B[n * 128 + k];
    red[h][k] = s;
    __syncthreads();
    if (h == 0) {
        float tot = red[0][k] + red[1][k] + red[2][k] + red[3][k];
        int cg = end - start;
        red[0][k] = tot / (float)(cg > 1 ? cg : 1);
    }
    __syncthreads();
    if (tid < 10) {
        float o = bl[tid];
        for (int j = 0; j < 128; j++) o = fmaf(red[0][j], Wl[j * 10 + tid], o);
        out[g * 10 + tid] = o;
    }
}

// ---------------- launch ----------------

extern "C" void kernel_launch(void* const* d_in, const int* in_sizes, int n_in,
                              void* d_out, int out_size, void* d_ws, size_t ws_size,
                              hipStream_t stream) {
    const float* x  = (const float*)d_in[0];
    const int* eidx = (const int*)d_in[1];
    const int* batch = (const int*)d_in[2];
    const float* W0 = (const float*)d_in[3];
    const float* b0 = (const float*)d_in[4];
    const float* W1 = (const float*)d_in[5];
    const float* b1 = (const float*)d_in[6];
    const float* W2 = (const float*)d_in[7];
    const float* b2 = (const float*)d_in[8];
    const float* Wl = (const float*)d_in[9];
    const float* bl = (const float*)d_in[10];

    int N = in_sizes[0] / 128;
    int E = in_sizes[1] / 2;
    int G = out_size / 10;
    const int* row = eidx;      // edge_index[0] = source
    const int* col = eidx + E;  // edge_index[1] = target

    char* w = (char*)d_ws;
    auto carve = [&](size_t bytes) -> void* {
        void* p = (void*)w;
        w += (bytes + 511) & ~(size_t)511;
        return p;
    };
    float* A    = (float*)carve((size_t)N * 128 * 4);
    float* Bb   = (float*)carve((size_t)N * 128 * 4);
    int*   cnt  = (int*)carve((size_t)N * 4);
    float* dinv = (float*)carve((size_t)N * 4);
    int*   ell  = (int*)carve((size_t)N * ELL_D * 4);

    // ELL build (re-done every call; deterministic work, summation order may permute within a node)
    hipMemsetAsync(cnt, 0, (size_t)N * 4, stream);
    k_fill_ell<<<(E + 255) / 256, 256, 0, stream>>>(row, col, cnt, ell, E);
    k_dinv<<<(N + 255) / 256, 256, 0, stream>>>(cnt, dinv, N);

    int gb = (N + 63) / 64;
    int ab = (N + 3) / 4;
    // layer 1
    k_gemm_scale<<<gb, 256, 0, stream>>>(x, W0, dinv, A, N);
    k_agg<<<ab, 256, 0, stream>>>(A, cnt, ell, dinv, b0, Bb, N);
    // layer 2
    k_gemm_scale<<<gb, 256, 0, stream>>>(Bb, W1, dinv, A, N);
    k_agg<<<ab, 256, 0, stream>>>(A, cnt, ell, dinv, b1, Bb, N);
    // layer 3
    k_gemm_scale<<<gb, 256, 0, stream>>>(Bb, W2, dinv, A, N);
    k_agg<<<ab, 256, 0, stream>>>(A, cnt, ell, dinv, b2, Bb, N);
    // pool + head
    k_pool<<<G, 512, 0, stream>>>(Bb, batch, Wl, bl, (float*)d_out, N);
}

// Round 3
// 675.378 us; speedup vs baseline: 1.1417x; 1.0092x over previous
//
#include <hip/hip_runtime.h>

#define ELL_D 64   // max in-degree slots; Poisson(16) => P(deg>=64) ~ 2e-18/node
#define CPAD 16    // one counter per 64B cache line to kill atomic line contention

// ---------------- ELL build ----------------

__global__ __launch_bounds__(256) void k_fill_ell(const int* __restrict__ col, const int* __restrict__ row,
                                                  int* __restrict__ cnt, int* __restrict__ ell, int E) {
    int t = blockIdx.x * 256 + threadIdx.x;
    int base = t * 4;
    if (base + 4 <= E) {
        int4 c4 = *(const int4*)(col + base);
        int4 r4 = *(const int4*)(row + base);
        int p0 = atomicAdd(&cnt[c4.x * CPAD], 1) & 63;
        int p1 = atomicAdd(&cnt[c4.y * CPAD], 1) & 63;
        int p2 = atomicAdd(&cnt[c4.z * CPAD], 1) & 63;
        int p3 = atomicAdd(&cnt[c4.w * CPAD], 1) & 63;
        ell[c4.x * ELL_D + p0] = r4.x;
        ell[c4.y * ELL_D + p1] = r4.y;
        ell[c4.z * ELL_D + p2] = r4.z;
        ell[c4.w * ELL_D + p3] = r4.w;
    } else {
        for (int e = base; e < E; e++) {
            int c = col[e];
            int pos = atomicAdd(&cnt[c * CPAD], 1) & 63;
            ell[c * ELL_D + pos] = row[e];
        }
    }
}

__global__ __launch_bounds__(256) void k_dinv(const int* __restrict__ cnt, float* __restrict__ dinv, int N) {
    int n = blockIdx.x * 256 + threadIdx.x;
    if (n < N) dinv[n] = 1.0f / sqrtf((float)(cnt[n * CPAD] + 1));  // +1 self loop; deg>=1 always
}

// ---------------- GEMM: A = (H @ W) * dinv[row] ----------------
// 64 rows/block, 256 threads, W staged in LDS (64KB), 4x8 register tile/thread.

__global__ __launch_bounds__(256) void k_gemm_scale(const float* __restrict__ H, const float* __restrict__ W,
                                                    const float* __restrict__ dinv, float* __restrict__ A, int N) {
    __shared__ float4 wl4[4096];  // 128x128 f32 = 64KB
    int tid = threadIdx.x;
    const float4* __restrict__ W4 = (const float4*)W;
#pragma unroll
    for (int i = 0; i < 16; i++) wl4[i * 256 + tid] = W4[i * 256 + tid];
    __syncthreads();

    int tc = tid & 15;   // col group: cols tc*8 .. tc*8+7
    int tr = tid >> 4;   // row group: 4 rows
    int rbase = blockIdx.x * 64 + tr * 4;

    const float4* __restrict__ H4 = (const float4*)H;
    float acc[4][8] = {};
    int r[4];
#pragma unroll
    for (int j = 0; j < 4; j++) {
        int rr = rbase + j;
        r[j] = (rr < N) ? rr : (N - 1);
    }

#pragma unroll 4
    for (int k4 = 0; k4 < 32; k4++) {
        union { float4 v; float f[4]; } hu[4];
#pragma unroll
        for (int j = 0; j < 4; j++) hu[j].v = H4[r[j] * 32 + k4];
#pragma unroll
        for (int kk = 0; kk < 4; kk++) {
            float4 w0 = wl4[(k4 * 4 + kk) * 32 + tc * 2];
            float4 w1 = wl4[(k4 * 4 + kk) * 32 + tc * 2 + 1];
#pragma unroll
            for (int j = 0; j < 4; j++) {
                float h = hu[j].f[kk];
                acc[j][0] = fmaf(h, w0.x, acc[j][0]);
                acc[j][1] = fmaf(h, w0.y, acc[j][1]);
                acc[j][2] = fmaf(h, w0.z, acc[j][2]);
                acc[j][3] = fmaf(h, w0.w, acc[j][3]);
                acc[j][4] = fmaf(h, w1.x, acc[j][4]);
                acc[j][5] = fmaf(h, w1.y, acc[j][5]);
                acc[j][6] = fmaf(h, w1.z, acc[j][6]);
                acc[j][7] = fmaf(h, w1.w, acc[j][7]);
            }
        }
    }

    float4* __restrict__ A4 = (float4*)A;
#pragma unroll
    for (int j = 0; j < 4; j++) {
        int rr = rbase + j;
        if (rr < N) {
            float dn = dinv[rr];
            A4[rr * 32 + tc * 2]     = make_float4(acc[j][0] * dn, acc[j][1] * dn, acc[j][2] * dn, acc[j][3] * dn);
            A4[rr * 32 + tc * 2 + 1] = make_float4(acc[j][4] * dn, acc[j][5] * dn, acc[j][6] * dn, acc[j][7] * dn);
        }
    }
}

// ---------------- Aggregation: B[n] = relu(dinv[n]*(sum_e A[src_e] + A[n]) + bias) ----------------
// One wave (64 lanes) per node; lane covers 2 feature columns (float2).
// 8 independent row-gathers in flight per wave per iteration.

__global__ __launch_bounds__(256) void k_agg(const float* __restrict__ A, const int* __restrict__ cnt,
                                             const int* __restrict__ ell, const float* __restrict__ dinv,
                                             const float* __restrict__ bias, float* __restrict__ Bout, int N) {
    int wid = blockIdx.x * 4 + (threadIdx.x >> 6);
    int lane = threadIdx.x & 63;
    if (wid >= N) return;
    const float2* __restrict__ A2 = (const float2*)A;
    int deg = cnt[wid * CPAD];
    const int4* __restrict__ l4 = (const int4*)(ell + wid * ELL_D);

    float2 self = A2[wid * 64 + lane];
    float ax = self.x, ay = self.y;

    int i = 0;
    for (; i + 8 <= deg; i += 8) {
        int4 a = l4[i >> 2];
        int4 b = l4[(i >> 2) + 1];
        float2 v0 = A2[a.x * 64 + lane];
        float2 v1 = A2[a.y * 64 + lane];
        float2 v2 = A2[a.z * 64 + lane];
        float2 v3 = A2[a.w * 64 + lane];
        float2 v4 = A2[b.x * 64 + lane];
        float2 v5 = A2[b.y * 64 + lane];
        float2 v6 = A2[b.z * 64 + lane];
        float2 v7 = A2[b.w * 64 + lane];
        ax += ((v0.x + v1.x) + (v2.x + v3.x)) + ((v4.x + v5.x) + (v6.x + v7.x));
        ay += ((v0.y + v1.y) + (v2.y + v3.y)) + ((v4.y + v5.y) + (v6.y + v7.y));
    }
    if (i + 4 <= deg) {
        int4 a = l4[i >> 2];
        float2 v0 = A2[a.x * 64 + lane];
        float2 v1 = A2[a.y * 64 + lane];
        float2 v2 = A2[a.z * 64 + lane];
        float2 v3 = A2[a.w * 64 + lane];
        ax += (v0.x + v1.x) + (v2.x + v3.x);
        ay += (v0.y + v1.y) + (v2.y + v3.y);
        i += 4;
    }
    const int* __restrict__ lst = (const int*)l4;
    for (; i < deg; i++) {
        int s0 = lst[i];
        float2 v = A2[s0 * 64 + lane];
        ax += v.x;
        ay += v.y;
    }

    float dn = dinv[wid];
    float bx = bias[2 * lane], by = bias[2 * lane + 1];
    float ox = fmaxf(fmaf(ax, dn, bx), 0.f);
    float oy = fmaxf(fmaf(ay, dn, by), 0.f);
    ((float2*)Bout)[wid * 64 + lane] = make_float2(ox, oy);
}

// ---------------- Pool (mean per graph, sorted batch) + head ----------------

__global__ __launch_bounds__(512) void k_pool(const float* __restrict__ B, const int* __restrict__ batch,
                                              const float* __restrict__ Wl, const float* __restrict__ bl,
                                              float* __restrict__ out, int N) {
    int g = blockIdx.x;
    int tid = threadIdx.x;
    int k = tid & 127, h = tid >> 7;  // h in 0..3
    __shared__ int se[2];
    __shared__ float red[4][128];
    if (tid < 2) {
        int target = g + tid;  // lower_bound(batch, target)
        int lo = 0, hi = N;
        while (lo < hi) {
            int mid = (lo + hi) >> 1;
            if (batch[mid] < target) lo = mid + 1; else hi = mid;
        }
        se[tid] = lo;
    }
    __syncthreads();
    int start = se[0], end = se[1];
    float s = 0.f;
    for (int n = start + h; n < end; n += 4) s += B[n * 128 + k];
    red[h][k] = s;
    __syncthreads();
    if (h == 0) {
        float tot = red[0][k] + red[1][k] + red[2][k] + red[3][k];
        int cg = end - start;
        red[0][k] = tot / (float)(cg > 1 ? cg : 1);
    }
    __syncthreads();
    if (tid < 10) {
        float o = bl[tid];
        for (int j = 0; j < 128; j++) o = fmaf(red[0][j], Wl[j * 10 + tid], o);
        out[g * 10 + tid] = o;
    }
}

// ---------------- launch ----------------

extern "C" void kernel_launch(void* const* d_in, const int* in_sizes, int n_in,
                              void* d_out, int out_size, void* d_ws, size_t ws_size,
                              hipStream_t stream) {
    const float* x  = (const float*)d_in[0];
    const int* eidx = (const int*)d_in[1];
    const int* batch = (const int*)d_in[2];
    const float* W0 = (const float*)d_in[3];
    const float* b0 = (const float*)d_in[4];
    const float* W1 = (const float*)d_in[5];
    const float* b1 = (const float*)d_in[6];
    const float* W2 = (const float*)d_in[7];
    const float* b2 = (const float*)d_in[8];
    const float* Wl = (const float*)d_in[9];
    const float* bl = (const float*)d_in[10];

    int N = in_sizes[0] / 128;
    int E = in_sizes[1] / 2;
    int G = out_size / 10;
    const int* row = eidx;      // edge_index[0] = source
    const int* col = eidx + E;  // edge_index[1] = target

    char* w = (char*)d_ws;
    auto carve = [&](size_t bytes) -> void* {
        void* p = (void*)w;
        w += (bytes + 511) & ~(size_t)511;
        return p;
    };
    float* A    = (float*)carve((size_t)N * 128 * 4);
    float* Bb   = (float*)carve((size_t)N * 128 * 4);
    int*   cnt  = (int*)carve((size_t)N * CPAD * 4);
    float* dinv = (float*)carve((size_t)N * 4);
    int*   ell  = (int*)carve((size_t)N * ELL_D * 4);

    // ELL build (re-done every call; deterministic work, summation order may permute within a node)
    hipMemsetAsync(cnt, 0, (size_t)N * CPAD * 4, stream);
    int ft = (E + 3) / 4;
    k_fill_ell<<<(ft + 255) / 256, 256, 0, stream>>>(col, row, cnt, ell, E);
    k_dinv<<<(N + 255) / 256, 256, 0, stream>>>(cnt, dinv, N);

    int gb = (N + 63) / 64;
    int ab = (N + 3) / 4;
    // layer 1
    k_gemm_scale<<<gb, 256, 0, stream>>>(x, W0, dinv, A, N);
    k_agg<<<ab, 256, 0, stream>>>(A, cnt, ell, dinv, b0, Bb, N);
    // layer 2
    k_gemm_scale<<<gb, 256, 0, stream>>>(Bb, W1, dinv, A, N);
    k_agg<<<ab, 256, 0, stream>>>(A, cnt, ell, dinv, b1, Bb, N);
    // layer 3
    k_gemm_scale<<<gb, 256, 0, stream>>>(Bb, W2, dinv, A, N);
    k_agg<<<ab, 256, 0, stream>>>(A, cnt, ell, dinv, b2, Bb, N);
    // pool + head
    k_pool<<<G, 512, 0, stream>>>(Bb, batch, Wl, bl, (float*)d_out, N);
}

// Round 4
// 609.873 us; speedup vs baseline: 1.2643x; 1.1074x over previous
//
#include <hip/hip_runtime.h>

#define ELL_D 64   // max in-degree slots; Poisson(16) => P(deg>=64) ~ 2e-18/node
#define CPAD 16    // one counter per 64B line (atomic isolation)

// ---------------- fused: gemm1 (even blocks) || ELL fill (odd blocks) ----------------
// gemm: A = H @ W (NO dinv scale - deferred to agg). 64 rows/block, 256 thr,
// W staged in LDS in two 32KB k-phases. fill: 4 edges/thread positional atomic.

__device__ __forceinline__ void gemm_body(int bid, const float* __restrict__ H,
                                          const float* __restrict__ W, float* __restrict__ A,
                                          int N, float4* wl4) {
    int tid = threadIdx.x;
    const float4* __restrict__ W4 = (const float4*)W;
    int tc = tid & 15;   // col group: cols tc*8 .. tc*8+7
    int tr = tid >> 4;   // row group: 4 rows
    int rbase = bid * 64 + tr * 4;

    const float4* __restrict__ H4 = (const float4*)H;
    float acc[4][8] = {};
    int r[4];
#pragma unroll
    for (int j = 0; j < 4; j++) {
        int rr = rbase + j;
        r[j] = (rr < N) ? rr : (N - 1);
    }

    for (int p = 0; p < 2; p++) {
        if (p) __syncthreads();
#pragma unroll
        for (int i = 0; i < 8; i++) wl4[i * 256 + tid] = W4[p * 2048 + i * 256 + tid];
        __syncthreads();
#pragma unroll 4
        for (int k4 = 0; k4 < 16; k4++) {
            union { float4 v; float f[4]; } hu[4];
#pragma unroll
            for (int j = 0; j < 4; j++) hu[j].v = H4[r[j] * 32 + p * 16 + k4];
#pragma unroll
            for (int kk = 0; kk < 4; kk++) {
                float4 w0 = wl4[(k4 * 4 + kk) * 32 + tc * 2];
                float4 w1 = wl4[(k4 * 4 + kk) * 32 + tc * 2 + 1];
#pragma unroll
                for (int j = 0; j < 4; j++) {
                    float h = hu[j].f[kk];
                    acc[j][0] = fmaf(h, w0.x, acc[j][0]);
                    acc[j][1] = fmaf(h, w0.y, acc[j][1]);
                    acc[j][2] = fmaf(h, w0.z, acc[j][2]);
                    acc[j][3] = fmaf(h, w0.w, acc[j][3]);
                    acc[j][4] = fmaf(h, w1.x, acc[j][4]);
                    acc[j][5] = fmaf(h, w1.y, acc[j][5]);
                    acc[j][6] = fmaf(h, w1.z, acc[j][6]);
                    acc[j][7] = fmaf(h, w1.w, acc[j][7]);
                }
            }
        }
    }

    float4* __restrict__ A4 = (float4*)A;
#pragma unroll
    for (int j = 0; j < 4; j++) {
        int rr = rbase + j;
        if (rr < N) {
            A4[rr * 32 + tc * 2]     = make_float4(acc[j][0], acc[j][1], acc[j][2], acc[j][3]);
            A4[rr * 32 + tc * 2 + 1] = make_float4(acc[j][4], acc[j][5], acc[j][6], acc[j][7]);
        }
    }
}

__device__ __forceinline__ void fill_body(int bid, const int* __restrict__ col, const int* __restrict__ row,
                                          int* __restrict__ cnt, int* __restrict__ ell, int E) {
    int t = bid * 256 + threadIdx.x;
    int base = t * 4;
    if (base + 4 <= E) {
        int4 c4 = *(const int4*)(col + base);
        int4 r4 = *(const int4*)(row + base);
        int p0 = atomicAdd(&cnt[c4.x * CPAD], 1) & 63;
        int p1 = atomicAdd(&cnt[c4.y * CPAD], 1) & 63;
        int p2 = atomicAdd(&cnt[c4.z * CPAD], 1) & 63;
        int p3 = atomicAdd(&cnt[c4.w * CPAD], 1) & 63;
        ell[c4.x * ELL_D + p0] = r4.x;
        ell[c4.y * ELL_D + p1] = r4.y;
        ell[c4.z * ELL_D + p2] = r4.z;
        ell[c4.w * ELL_D + p3] = r4.w;
    } else {
        for (int e = base; e < E; e++) {
            int c = col[e];
            int pos = atomicAdd(&cnt[c * CPAD], 1) & 63;
            ell[c * ELL_D + pos] = row[e];
        }
    }
}

__global__ __launch_bounds__(256) void k_fused_gemm_fill(const float* __restrict__ H, const float* __restrict__ W,
                                                         float* __restrict__ A,
                                                         const int* __restrict__ col, const int* __restrict__ row,
                                                         int* __restrict__ cnt, int* __restrict__ ell,
                                                         int N, int E, int gb, int fb) {
    __shared__ float4 wl4[2048];  // 32KB
    int half = blockIdx.x >> 1;
    if (!(blockIdx.x & 1)) {
        if (half < gb) gemm_body(half, H, W, A, N, wl4);
    } else {
        if (half < fb) fill_body(half, col, row, cnt, ell, E);
    }
}

// standalone gemm for layers 2,3 (same body)
__global__ __launch_bounds__(256) void k_gemm(const float* __restrict__ H, const float* __restrict__ W,
                                              float* __restrict__ A, int N) {
    __shared__ float4 wl4[2048];
    gemm_body(blockIdx.x, H, W, A, N, wl4);
}

__global__ __launch_bounds__(256) void k_dinv(const int* __restrict__ cnt, float* __restrict__ dinv, int N) {
    int n = blockIdx.x * 256 + threadIdx.x;
    if (n < N) dinv[n] = 1.0f / sqrtf((float)(cnt[n * CPAD] + 1));  // +1 self loop
}

// ---------------- Aggregation ----------------
// B[n] = relu(dinv[n] * (sum_{slot=0..deg} A[src]*dinv[src]) + bias), slot=deg is the
// virtual self edge (src=n). One wave per node; half-waves gather 2 edges/instr as float4.

__global__ __launch_bounds__(256) void k_agg(const float* __restrict__ A, const int* __restrict__ cnt,
                                             const int* __restrict__ ell, const float* __restrict__ dinv,
                                             const float* __restrict__ bias, float* __restrict__ Bout, int N) {
    int wid = blockIdx.x * 4 + (threadIdx.x >> 6);
    int lane = threadIdx.x & 63;
    if (wid >= N) return;
    int hi = lane >> 5, li = lane & 31;
    const float4* __restrict__ A4 = (const float4*)A;
    int deg = cnt[wid * CPAD];
    float dn = dinv[wid];
    const int* __restrict__ lst = ell + wid * ELL_D;

    int total = deg + 1;          // + virtual self edge at slot==deg
    int pairs = (total + 1) >> 1; // 2 slots per pair (one per half-wave)

    float4 a0 = {0,0,0,0}, a1 = {0,0,0,0}, a2 = {0,0,0,0}, a3 = {0,0,0,0};
    int i = 0;
    for (; i + 4 <= pairs; i += 4) {
        int s0 = 2 * i + hi, s1 = s0 + 2, s2 = s0 + 4, s3 = s0 + 6;
        int e0 = (s0 < deg) ? lst[s0] : wid;
        int e1 = (s1 < deg) ? lst[s1] : wid;
        int e2 = (s2 < deg) ? lst[s2] : wid;
        int e3 = (s3 < deg) ? lst[s3] : wid;
        float d0 = (s0 < total) ? dinv[e0] : 0.f;
        float d1 = (s1 < total) ? dinv[e1] : 0.f;
        float d2 = (s2 < total) ? dinv[e2] : 0.f;
        float d3 = (s3 < total) ? dinv[e3] : 0.f;
        float4 v0 = A4[e0 * 32 + li];
        float4 v1 = A4[e1 * 32 + li];
        float4 v2 = A4[e2 * 32 + li];
        float4 v3 = A4[e3 * 32 + li];
        a0.x = fmaf(v0.x, d0, a0.x); a0.y = fmaf(v0.y, d0, a0.y); a0.z = fmaf(v0.z, d0, a0.z); a0.w = fmaf(v0.w, d0, a0.w);
        a1.x = fmaf(v1.x, d1, a1.x); a1.y = fmaf(v1.y, d1, a1.y); a1.z = fmaf(v1.z, d1, a1.z); a1.w = fmaf(v1.w, d1, a1.w);
        a2.x = fmaf(v2.x, d2, a2.x); a2.y = fmaf(v2.y, d2, a2.y); a2.z = fmaf(v2.z, d2, a2.z); a2.w = fmaf(v2.w, d2, a2.w);
        a3.x = fmaf(v3.x, d3, a3.x); a3.y = fmaf(v3.y, d3, a3.y); a3.z = fmaf(v3.z, d3, a3.z); a3.w = fmaf(v3.w, d3, a3.w);
    }
    for (; i < pairs; i++) {
        int s0 = 2 * i + hi;
        int e0 = (s0 < deg) ? lst[s0] : wid;
        float d0 = (s0 < total) ? dinv[e0] : 0.f;
        float4 v0 = A4[e0 * 32 + li];
        a0.x = fmaf(v0.x, d0, a0.x); a0.y = fmaf(v0.y, d0, a0.y); a0.z = fmaf(v0.z, d0, a0.z); a0.w = fmaf(v0.w, d0, a0.w);
    }
    a0.x = (a0.x + a1.x) + (a2.x + a3.x);
    a0.y = (a0.y + a1.y) + (a2.y + a3.y);
    a0.z = (a0.z + a1.z) + (a2.z + a3.z);
    a0.w = (a0.w + a1.w) + (a2.w + a3.w);
    // combine halves
    a0.x += __shfl_xor(a0.x, 32, 64);
    a0.y += __shfl_xor(a0.y, 32, 64);
    a0.z += __shfl_xor(a0.z, 32, 64);
    a0.w += __shfl_xor(a0.w, 32, 64);

    if (hi == 0) {
        const float4* __restrict__ b4 = (const float4*)bias;
        float4 bb = b4[li];
        float4 o;
        o.x = fmaxf(fmaf(a0.x, dn, bb.x), 0.f);
        o.y = fmaxf(fmaf(a0.y, dn, bb.y), 0.f);
        o.z = fmaxf(fmaf(a0.z, dn, bb.z), 0.f);
        o.w = fmaxf(fmaf(a0.w, dn, bb.w), 0.f);
        ((float4*)Bout)[wid * 32 + li] = o;
    }
}

// ---------------- Pool (mean per graph, sorted batch) + head ----------------

__global__ __launch_bounds__(512) void k_pool(const float* __restrict__ B, const int* __restrict__ batch,
                                              const float* __restrict__ Wl, const float* __restrict__ bl,
                                              float* __restrict__ out, int N) {
    int g = blockIdx.x;
    int tid = threadIdx.x;
    int k = tid & 127, h = tid >> 7;  // h in 0..3
    __shared__ int se[2];
    __shared__ float red[4][128];
    if (tid < 2) {
        int target = g + tid;  // lower_bound(batch, target)
        int lo = 0, hi = N;
        while (lo < hi) {
            int mid = (lo + hi) >> 1;
            if (batch[mid] < target) lo = mid + 1; else hi = mid;
        }
        se[tid] = lo;
    }
    __syncthreads();
    int start = se[0], end = se[1];
    float s = 0.f;
    for (int n = start + h; n < end; n += 4) s += B[n * 128 + k];
    red[h][k] = s;
    __syncthreads();
    if (h == 0) {
        float tot = red[0][k] + red[1][k] + red[2][k] + red[3][k];
        int cg = end - start;
        red[0][k] = tot / (float)(cg > 1 ? cg : 1);
    }
    __syncthreads();
    if (tid < 10) {
        float o = bl[tid];
        for (int j = 0; j < 128; j++) o = fmaf(red[0][j], Wl[j * 10 + tid], o);
        out[g * 10 + tid] = o;
    }
}

// ---------------- launch ----------------

extern "C" void kernel_launch(void* const* d_in, const int* in_sizes, int n_in,
                              void* d_out, int out_size, void* d_ws, size_t ws_size,
                              hipStream_t stream) {
    const float* x  = (const float*)d_in[0];
    const int* eidx = (const int*)d_in[1];
    const int* batch = (const int*)d_in[2];
    const float* W0 = (const float*)d_in[3];
    const float* b0 = (const float*)d_in[4];
    const float* W1 = (const float*)d_in[5];
    const float* b1 = (const float*)d_in[6];
    const float* W2 = (const float*)d_in[7];
    const float* b2 = (const float*)d_in[8];
    const float* Wl = (const float*)d_in[9];
    const float* bl = (const float*)d_in[10];

    int N = in_sizes[0] / 128;
    int E = in_sizes[1] / 2;
    int G = out_size / 10;
    const int* row = eidx;      // edge_index[0] = source
    const int* col = eidx + E;  // edge_index[1] = target

    char* w = (char*)d_ws;
    auto carve = [&](size_t bytes) -> void* {
        void* p = (void*)w;
        w += (bytes + 511) & ~(size_t)511;
        return p;
    };
    float* A    = (float*)carve((size_t)N * 128 * 4);
    float* Bb   = (float*)carve((size_t)N * 128 * 4);
    int*   cnt  = (int*)carve((size_t)N * CPAD * 4);
    float* dinv = (float*)carve((size_t)N * 4);
    int*   ell  = (int*)carve((size_t)N * ELL_D * 4 + 512);

    int gb = (N + 63) / 64;
    int ft = (E + 3) / 4;
    int fb = (ft + 255) / 256;
    int M  = (gb > fb) ? gb : fb;

    hipMemsetAsync(cnt, 0, (size_t)N * CPAD * 4, stream);
    // layer 1 gemm overlapped with ELL build (independent work, fat kernel)
    k_fused_gemm_fill<<<2 * M, 256, 0, stream>>>(x, W0, A, col, row, cnt, ell, N, E, gb, fb);
    k_dinv<<<(N + 255) / 256, 256, 0, stream>>>(cnt, dinv, N);

    int ab = (N + 3) / 4;
    k_agg<<<ab, 256, 0, stream>>>(A, cnt, ell, dinv, b0, Bb, N);
    // layer 2
    k_gemm<<<gb, 256, 0, stream>>>(Bb, W1, A, N);
    k_agg<<<ab, 256, 0, stream>>>(A, cnt, ell, dinv, b1, Bb, N);
    // layer 3
    k_gemm<<<gb, 256, 0, stream>>>(Bb, W2, A, N);
    k_agg<<<ab, 256, 0, stream>>>(A, cnt, ell, dinv, b2, Bb, N);
    // pool + head
    k_pool<<<G, 512, 0, stream>>>(Bb, batch, Wl, bl, (float*)d_out, N);
}

// Round 5
// 506.720 us; speedup vs baseline: 1.5217x; 1.2036x over previous
//
#include <hip/hip_runtime.h>
#include <hip/hip_bf16.h>

#define ELL_D 64   // max in-degree slots; Poisson(16) => P(deg>=64) ~ 2e-18/node

__device__ __forceinline__ unsigned short f2bf(float f) {
    __hip_bfloat16 h = __float2bfloat16(f);  // RNE
    return *(unsigned short*)&h;
}
__device__ __forceinline__ float bf2f(unsigned short u) {
    unsigned int v = ((unsigned int)u) << 16;
    return __uint_as_float(v);
}

// ---------------- fused: gemm1 (even blocks) || ELL fill (odd blocks) ----------------
// gemm: A(bf16) = H @ W (dinv deferred to agg). 64 rows/block, 256 thr,
// W staged in LDS in two 32KB k-phases. Lane tc owns cols [4tc,4tc+4) u [64+4tc,...)
// so LDS reads are 16 consecutive float4 chunks (conflict-free).

__device__ __forceinline__ void gemm_body(int bid, const float* __restrict__ H,
                                          const float* __restrict__ W, unsigned short* __restrict__ A,
                                          int N, float4* wl4) {
    int tid = threadIdx.x;
    const float4* __restrict__ W4 = (const float4*)W;
    int tc = tid & 15;   // col group
    int tr = tid >> 4;   // row group: 4 rows
    int rbase = bid * 64 + tr * 4;

    const float4* __restrict__ H4 = (const float4*)H;
    float acc[4][8] = {};
    int r[4];
#pragma unroll
    for (int j = 0; j < 4; j++) {
        int rr = rbase + j;
        r[j] = (rr < N) ? rr : (N - 1);
    }

    for (int p = 0; p < 2; p++) {
        if (p) __syncthreads();
#pragma unroll
        for (int i = 0; i < 8; i++) wl4[i * 256 + tid] = W4[p * 2048 + i * 256 + tid];
        __syncthreads();
#pragma unroll 4
        for (int k4 = 0; k4 < 16; k4++) {
            union { float4 v; float f[4]; } hu[4];
#pragma unroll
            for (int j = 0; j < 4; j++) hu[j].v = H4[r[j] * 32 + p * 16 + k4];
#pragma unroll
            for (int kk = 0; kk < 4; kk++) {
                float4 w0 = wl4[(k4 * 4 + kk) * 32 + tc];        // cols 4tc..4tc+3
                float4 w1 = wl4[(k4 * 4 + kk) * 32 + 16 + tc];   // cols 64+4tc..
#pragma unroll
                for (int j = 0; j < 4; j++) {
                    float h = hu[j].f[kk];
                    acc[j][0] = fmaf(h, w0.x, acc[j][0]);
                    acc[j][1] = fmaf(h, w0.y, acc[j][1]);
                    acc[j][2] = fmaf(h, w0.z, acc[j][2]);
                    acc[j][3] = fmaf(h, w0.w, acc[j][3]);
                    acc[j][4] = fmaf(h, w1.x, acc[j][4]);
                    acc[j][5] = fmaf(h, w1.y, acc[j][5]);
                    acc[j][6] = fmaf(h, w1.z, acc[j][6]);
                    acc[j][7] = fmaf(h, w1.w, acc[j][7]);
                }
            }
        }
    }

    ushort4* __restrict__ A4 = (ushort4*)A;
#pragma unroll
    for (int j = 0; j < 4; j++) {
        int rr = rbase + j;
        if (rr < N) {
            A4[rr * 32 + tc]      = make_ushort4(f2bf(acc[j][0]), f2bf(acc[j][1]), f2bf(acc[j][2]), f2bf(acc[j][3]));
            A4[rr * 32 + 16 + tc] = make_ushort4(f2bf(acc[j][4]), f2bf(acc[j][5]), f2bf(acc[j][6]), f2bf(acc[j][7]));
        }
    }
}

__device__ __forceinline__ void fill_body(int bid, const int* __restrict__ col, const int* __restrict__ row,
                                          int* __restrict__ cnt, int* __restrict__ ell, int E) {
    int t = bid * 256 + threadIdx.x;
    int base = t * 4;
    if (base + 4 <= E) {
        int4 c4 = *(const int4*)(col + base);
        int4 r4 = *(const int4*)(row + base);
        int p0 = atomicAdd(&cnt[c4.x], 1) & 63;
        int p1 = atomicAdd(&cnt[c4.y], 1) & 63;
        int p2 = atomicAdd(&cnt[c4.z], 1) & 63;
        int p3 = atomicAdd(&cnt[c4.w], 1) & 63;
        ell[c4.x * ELL_D + p0] = r4.x;
        ell[c4.y * ELL_D + p1] = r4.y;
        ell[c4.z * ELL_D + p2] = r4.z;
        ell[c4.w * ELL_D + p3] = r4.w;
    } else {
        for (int e = base; e < E; e++) {
            int c = col[e];
            int pos = atomicAdd(&cnt[c], 1) & 63;
            ell[c * ELL_D + pos] = row[e];
        }
    }
}

__global__ __launch_bounds__(256) void k_fused_gemm_fill(const float* __restrict__ H, const float* __restrict__ W,
                                                         unsigned short* __restrict__ A,
                                                         const int* __restrict__ col, const int* __restrict__ row,
                                                         int* __restrict__ cnt, int* __restrict__ ell,
                                                         int N, int E, int gb, int fb) {
    __shared__ float4 wl4[2048];  // 32KB
    int half = blockIdx.x >> 1;
    if (!(blockIdx.x & 1)) {
        if (half < gb) gemm_body(half, H, W, A, N, wl4);
    } else {
        if (half < fb) fill_body(half, col, row, cnt, ell, E);
    }
}

__global__ __launch_bounds__(256) void k_gemm(const float* __restrict__ H, const float* __restrict__ W,
                                              unsigned short* __restrict__ A, int N) {
    __shared__ float4 wl4[2048];
    gemm_body(blockIdx.x, H, W, A, N, wl4);
}

__global__ __launch_bounds__(256) void k_dinv(const int* __restrict__ cnt, float* __restrict__ dinv, int N) {
    int n = blockIdx.x * 256 + threadIdx.x;
    if (n < N) dinv[n] = 1.0f / sqrtf((float)(cnt[n] + 1));  // +1 self loop
}

// ---------------- Aggregation ----------------
// B[n] = relu(dinv[n] * (sum_{slot=0..deg} A[src]*dinv[src]) + bias); slot==deg is the
// virtual self edge. One wave per node; half-waves gather 2 edges/instr; rows are bf16 (256B).

__global__ __launch_bounds__(256) void k_agg(const unsigned short* __restrict__ A, const int* __restrict__ cnt,
                                             const int* __restrict__ ell, const float* __restrict__ dinv,
                                             const float* __restrict__ bias, float* __restrict__ Bout, int N) {
    int wid = blockIdx.x * 4 + (threadIdx.x >> 6);
    int lane = threadIdx.x & 63;
    if (wid >= N) return;
    int hi = lane >> 5, li = lane & 31;
    const ushort4* __restrict__ A4 = (const ushort4*)A;  // 4 bf16 per lane, 32 lanes = 256B row
    int deg = cnt[wid];
    float dn = dinv[wid];
    const int* __restrict__ lst = ell + wid * ELL_D;

    int total = deg + 1;
    int pairs = (total + 1) >> 1;

    float4 a0 = {0,0,0,0}, a1 = {0,0,0,0}, a2 = {0,0,0,0}, a3 = {0,0,0,0};
    int i = 0;
    for (; i + 4 <= pairs; i += 4) {
        int s0 = 2 * i + hi, s1 = s0 + 2, s2 = s0 + 4, s3 = s0 + 6;
        int e0 = (s0 < deg) ? lst[s0] : wid;
        int e1 = (s1 < deg) ? lst[s1] : wid;
        int e2 = (s2 < deg) ? lst[s2] : wid;
        int e3 = (s3 < deg) ? lst[s3] : wid;
        float d0 = (s0 < total) ? dinv[e0] : 0.f;
        float d1 = (s1 < total) ? dinv[e1] : 0.f;
        float d2 = (s2 < total) ? dinv[e2] : 0.f;
        float d3 = (s3 < total) ? dinv[e3] : 0.f;
        ushort4 v0 = A4[e0 * 32 + li];
        ushort4 v1 = A4[e1 * 32 + li];
        ushort4 v2 = A4[e2 * 32 + li];
        ushort4 v3 = A4[e3 * 32 + li];
        a0.x = fmaf(bf2f(v0.x), d0, a0.x); a0.y = fmaf(bf2f(v0.y), d0, a0.y);
        a0.z = fmaf(bf2f(v0.z), d0, a0.z); a0.w = fmaf(bf2f(v0.w), d0, a0.w);
        a1.x = fmaf(bf2f(v1.x), d1, a1.x); a1.y = fmaf(bf2f(v1.y), d1, a1.y);
        a1.z = fmaf(bf2f(v1.z), d1, a1.z); a1.w = fmaf(bf2f(v1.w), d1, a1.w);
        a2.x = fmaf(bf2f(v2.x), d2, a2.x); a2.y = fmaf(bf2f(v2.y), d2, a2.y);
        a2.z = fmaf(bf2f(v2.z), d2, a2.z); a2.w = fmaf(bf2f(v2.w), d2, a2.w);
        a3.x = fmaf(bf2f(v3.x), d3, a3.x); a3.y = fmaf(bf2f(v3.y), d3, a3.y);
        a3.z = fmaf(bf2f(v3.z), d3, a3.z); a3.w = fmaf(bf2f(v3.w), d3, a3.w);
    }
    for (; i < pairs; i++) {
        int s0 = 2 * i + hi;
        int e0 = (s0 < deg) ? lst[s0] : wid;
        float d0 = (s0 < total) ? dinv[e0] : 0.f;
        ushort4 v0 = A4[e0 * 32 + li];
        a0.x = fmaf(bf2f(v0.x), d0, a0.x); a0.y = fmaf(bf2f(v0.y), d0, a0.y);
        a0.z = fmaf(bf2f(v0.z), d0, a0.z); a0.w = fmaf(bf2f(v0.w), d0, a0.w);
    }
    a0.x = (a0.x + a1.x) + (a2.x + a3.x);
    a0.y = (a0.y + a1.y) + (a2.y + a3.y);
    a0.z = (a0.z + a1.z) + (a2.z + a3.z);
    a0.w = (a0.w + a1.w) + (a2.w + a3.w);
    a0.x += __shfl_xor(a0.x, 32, 64);
    a0.y += __shfl_xor(a0.y, 32, 64);
    a0.z += __shfl_xor(a0.z, 32, 64);
    a0.w += __shfl_xor(a0.w, 32, 64);

    if (hi == 0) {
        const float4* __restrict__ b4 = (const float4*)bias;
        float4 bb = b4[li];
        float4 o;
        o.x = fmaxf(fmaf(a0.x, dn, bb.x), 0.f);
        o.y = fmaxf(fmaf(a0.y, dn, bb.y), 0.f);
        o.z = fmaxf(fmaf(a0.z, dn, bb.z), 0.f);
        o.w = fmaxf(fmaf(a0.w, dn, bb.w), 0.f);
        ((float4*)Bout)[wid * 32 + li] = o;
    }
}

// ---------------- Pool (mean per graph, sorted batch) + head ----------------

__global__ __launch_bounds__(512) void k_pool(const float* __restrict__ B, const int* __restrict__ batch,
                                              const float* __restrict__ Wl, const float* __restrict__ bl,
                                              float* __restrict__ out, int N) {
    int g = blockIdx.x;
    int tid = threadIdx.x;
    int k = tid & 127, h = tid >> 7;  // h in 0..3
    __shared__ int se[2];
    __shared__ float red[4][128];
    if (tid < 2) {
        int target = g + tid;  // lower_bound(batch, target)
        int lo = 0, hi = N;
        while (lo < hi) {
            int mid = (lo + hi) >> 1;
            if (batch[mid] < target) lo = mid + 1; else hi = mid;
        }
        se[tid] = lo;
    }
    __syncthreads();
    int start = se[0], end = se[1];
    float s = 0.f;
    for (int n = start + h; n < end; n += 4) s += B[n * 128 + k];
    red[h][k] = s;
    __syncthreads();
    if (h == 0) {
        float tot = red[0][k] + red[1][k] + red[2][k] + red[3][k];
        int cg = end - start;
        red[0][k] = tot / (float)(cg > 1 ? cg : 1);
    }
    __syncthreads();
    if (tid < 10) {
        float o = bl[tid];
        for (int j = 0; j < 128; j++) o = fmaf(red[0][j], Wl[j * 10 + tid], o);
        out[g * 10 + tid] = o;
    }
}

// ---------------- launch ----------------

extern "C" void kernel_launch(void* const* d_in, const int* in_sizes, int n_in,
                              void* d_out, int out_size, void* d_ws, size_t ws_size,
                              hipStream_t stream) {
    const float* x  = (const float*)d_in[0];
    const int* eidx = (const int*)d_in[1];
    const int* batch = (const int*)d_in[2];
    const float* W0 = (const float*)d_in[3];
    const float* b0 = (const float*)d_in[4];
    const float* W1 = (const float*)d_in[5];
    const float* b1 = (const float*)d_in[6];
    const float* W2 = (const float*)d_in[7];
    const float* b2 = (const float*)d_in[8];
    const float* Wl = (const float*)d_in[9];
    const float* bl = (const float*)d_in[10];

    int N = in_sizes[0] / 128;
    int E = in_sizes[1] / 2;
    int G = out_size / 10;
    const int* row = eidx;      // edge_index[0] = source
    const int* col = eidx + E;  // edge_index[1] = target

    char* w = (char*)d_ws;
    auto carve = [&](size_t bytes) -> void* {
        void* p = (void*)w;
        w += (bytes + 511) & ~(size_t)511;
        return p;
    };
    unsigned short* A = (unsigned short*)carve((size_t)N * 128 * 2);  // bf16
    float* Bb   = (float*)carve((size_t)N * 128 * 4);
    int*   cnt  = (int*)carve((size_t)N * 4);
    float* dinv = (float*)carve((size_t)N * 4);
    int*   ell  = (int*)carve((size_t)N * ELL_D * 4);

    int gb = (N + 63) / 64;
    int ft = (E + 3) / 4;
    int fb = (ft + 255) / 256;
    int M  = (gb > fb) ? gb : fb;

    hipMemsetAsync(cnt, 0, (size_t)N * 4, stream);
    // layer 1 gemm overlapped with ELL build (independent work, fat kernel)
    k_fused_gemm_fill<<<2 * M, 256, 0, stream>>>(x, W0, A, col, row, cnt, ell, N, E, gb, fb);
    k_dinv<<<(N + 255) / 256, 256, 0, stream>>>(cnt, dinv, N);

    int ab = (N + 3) / 4;
    k_agg<<<ab, 256, 0, stream>>>(A, cnt, ell, dinv, b0, Bb, N);
    // layer 2
    k_gemm<<<gb, 256, 0, stream>>>(Bb, W1, A, N);
    k_agg<<<ab, 256, 0, stream>>>(A, cnt, ell, dinv, b1, Bb, N);
    // layer 3
    k_gemm<<<gb, 256, 0, stream>>>(Bb, W2, A, N);
    k_agg<<<ab, 256, 0, stream>>>(A, cnt, ell, dinv, b2, Bb, N);
    // pool + head
    k_pool<<<G, 512, 0, stream>>>(Bb, batch, Wl, bl, (float*)d_out, N);
}

// Round 6
// 411.942 us; speedup vs baseline: 1.8718x; 1.2301x over previous
//
#include <hip/hip_runtime.h>
#include <hip/hip_bf16.h>

#define ELL_D 64   // max in-degree slots; Poisson(16) => P(deg>=64) ~ 2e-18/node

typedef __attribute__((ext_vector_type(8))) short short8;
typedef __attribute__((ext_vector_type(4))) float f32x4;

__device__ __forceinline__ unsigned short f2bf(float f) {
    __hip_bfloat16 h = __float2bfloat16(f);  // RNE
    return *(unsigned short*)&h;
}
__device__ __forceinline__ float bf2f(unsigned short u) {
    unsigned int v = ((unsigned int)u) << 16;
    return __uint_as_float(v);
}

// ---------------- fused: gemm1 (even blocks) || ELL fill (odd blocks) ----------------
// gemm1: A(bf16, UNSCALED) = x @ W0, f32 vector math (hidden under fill's idle VALU).

__device__ __forceinline__ void gemm_body(int bid, const float* __restrict__ H,
                                          const float* __restrict__ W, unsigned short* __restrict__ A,
                                          int N, float4* wl4) {
    int tid = threadIdx.x;
    const float4* __restrict__ W4 = (const float4*)W;
    int tc = tid & 15;
    int tr = tid >> 4;
    int rbase = bid * 64 + tr * 4;

    const float4* __restrict__ H4 = (const float4*)H;
    float acc[4][8] = {};
    int r[4];
#pragma unroll
    for (int j = 0; j < 4; j++) {
        int rr = rbase + j;
        r[j] = (rr < N) ? rr : (N - 1);
    }

    for (int p = 0; p < 2; p++) {
        if (p) __syncthreads();
#pragma unroll
        for (int i = 0; i < 8; i++) wl4[i * 256 + tid] = W4[p * 2048 + i * 256 + tid];
        __syncthreads();
#pragma unroll 4
        for (int k4 = 0; k4 < 16; k4++) {
            union { float4 v; float f[4]; } hu[4];
#pragma unroll
            for (int j = 0; j < 4; j++) hu[j].v = H4[r[j] * 32 + p * 16 + k4];
#pragma unroll
            for (int kk = 0; kk < 4; kk++) {
                float4 w0 = wl4[(k4 * 4 + kk) * 32 + tc];
                float4 w1 = wl4[(k4 * 4 + kk) * 32 + 16 + tc];
#pragma unroll
                for (int j = 0; j < 4; j++) {
                    float h = hu[j].f[kk];
                    acc[j][0] = fmaf(h, w0.x, acc[j][0]);
                    acc[j][1] = fmaf(h, w0.y, acc[j][1]);
                    acc[j][2] = fmaf(h, w0.z, acc[j][2]);
                    acc[j][3] = fmaf(h, w0.w, acc[j][3]);
                    acc[j][4] = fmaf(h, w1.x, acc[j][4]);
                    acc[j][5] = fmaf(h, w1.y, acc[j][5]);
                    acc[j][6] = fmaf(h, w1.z, acc[j][6]);
                    acc[j][7] = fmaf(h, w1.w, acc[j][7]);
                }
            }
        }
    }

    ushort4* __restrict__ A4 = (ushort4*)A;
#pragma unroll
    for (int j = 0; j < 4; j++) {
        int rr = rbase + j;
        if (rr < N) {
            A4[rr * 32 + tc]      = make_ushort4(f2bf(acc[j][0]), f2bf(acc[j][1]), f2bf(acc[j][2]), f2bf(acc[j][3]));
            A4[rr * 32 + 16 + tc] = make_ushort4(f2bf(acc[j][4]), f2bf(acc[j][5]), f2bf(acc[j][6]), f2bf(acc[j][7]));
        }
    }
}

__device__ __forceinline__ void fill_body(int bid, const int* __restrict__ col, const int* __restrict__ row,
                                          int* __restrict__ cnt, int* __restrict__ ell, int E) {
    int t = bid * 256 + threadIdx.x;
    int base = t * 4;
    if (base + 4 <= E) {
        int4 c4 = *(const int4*)(col + base);
        int4 r4 = *(const int4*)(row + base);
        int p0 = atomicAdd(&cnt[c4.x], 1) & 63;
        int p1 = atomicAdd(&cnt[c4.y], 1) & 63;
        int p2 = atomicAdd(&cnt[c4.z], 1) & 63;
        int p3 = atomicAdd(&cnt[c4.w], 1) & 63;
        ell[c4.x * ELL_D + p0] = r4.x;
        ell[c4.y * ELL_D + p1] = r4.y;
        ell[c4.z * ELL_D + p2] = r4.z;
        ell[c4.w * ELL_D + p3] = r4.w;
    } else {
        for (int e = base; e < E; e++) {
            int c = col[e];
            int pos = atomicAdd(&cnt[c], 1) & 63;
            ell[c * ELL_D + pos] = row[e];
        }
    }
}

__global__ __launch_bounds__(256) void k_fused_gemm_fill(const float* __restrict__ H, const float* __restrict__ W,
                                                         unsigned short* __restrict__ A,
                                                         const int* __restrict__ col, const int* __restrict__ row,
                                                         int* __restrict__ cnt, int* __restrict__ ell,
                                                         int N, int E, int gb, int fb) {
    __shared__ float4 wl4[2048];  // 32KB
    int half = blockIdx.x >> 1;
    if (!(blockIdx.x & 1)) {
        if (half < gb) gemm_body(half, H, W, A, N, wl4);
    } else {
        if (half < fb) fill_body(half, col, row, cnt, ell, E);
    }
}

// ---------------- W prep: WT (bf16, transposed) for layers 2,3 ----------------
__global__ __launch_bounds__(256) void k_prep_wt(const float* __restrict__ W1, const float* __restrict__ W2,
                                                 unsigned short* __restrict__ WT1, unsigned short* __restrict__ WT2) {
    const float* W = blockIdx.x ? W2 : W1;
    unsigned short* WT = blockIdx.x ? WT2 : WT1;
    for (int i = threadIdx.x; i < 16384; i += 256) {
        int c = i >> 7, k = i & 127;
        WT[i] = f2bf(W[k * 128 + c]);  // WT[c][k] = W[k][c]
    }
}

// ---------------- dinv + scale layer-1 A in place: A[n] *= dinv[n] ----------------
__global__ __launch_bounds__(256) void k_dinv_scaleA(const int* __restrict__ cnt, float* __restrict__ dinv,
                                                     unsigned short* __restrict__ A, int N) {
    int node = blockIdx.x * 8 + (threadIdx.x >> 5);
    int li = threadIdx.x & 31;
    if (node >= N) return;
    float dn = 1.0f / sqrtf((float)(cnt[node] + 1));
    if (li == 0) dinv[node] = dn;
    ushort4* Ap = (ushort4*)A + (size_t)node * 32 + li;
    ushort4 v = *Ap;
    v.x = f2bf(bf2f(v.x) * dn);
    v.y = f2bf(bf2f(v.y) * dn);
    v.z = f2bf(bf2f(v.z) * dn);
    v.w = f2bf(bf2f(v.w) * dn);
    *Ap = v;
}

// ---------------- MFMA GEMM (layers 2,3): A' = bf16((Bb @ W) * dinv[row]) ----------------
// Bb bf16 row-major [N][128], WT bf16 [col][k]. Per wave: 16 rows x 128 cols.
// mfma_f32_16x16x32_bf16: A-frag lane&15=row, B-frag lane&15=col, k=(lane>>4)*8+e
// (any consistent k-permutation cancels between A and B). D: col=lane&15, row=4*(lane>>4)+reg.

__global__ __launch_bounds__(256) void k_gemm_mfma(const unsigned short* __restrict__ H,
                                                   const unsigned short* __restrict__ WT,
                                                   const float* __restrict__ dinv,
                                                   unsigned short* __restrict__ A, int N) {
    __shared__ float ep[4 * 16 * 132];  // per-wave 16x128 f32, row stride 132
    int tid = threadIdx.x, w = tid >> 6, l = tid & 63;
    int rbase = blockIdx.x * 64 + w * 16;
    int lrow = l & 15, lk = l >> 4;

    int r = rbase + lrow;
    if (r >= N) r = N - 1;
    const short8* __restrict__ Hp = (const short8*)(H + (size_t)r * 128);
    short8 af[4];
#pragma unroll
    for (int kc = 0; kc < 4; kc++) af[kc] = Hp[kc * 4 + lk];  // k = kc*32 + lk*8 .. +7

    f32x4 acc[8];
#pragma unroll
    for (int t = 0; t < 8; t++) {
        f32x4 a = {0.f, 0.f, 0.f, 0.f};
        const short8* __restrict__ Wp = (const short8*)(WT + (size_t)(t * 16 + lrow) * 128);
#pragma unroll
        for (int kc = 0; kc < 4; kc++) {
            short8 bf = Wp[kc * 4 + lk];
            a = __builtin_amdgcn_mfma_f32_16x16x32_bf16(af[kc], bf, a, 0, 0, 0);
        }
        acc[t] = a;
    }

    // stage D to LDS (f32), per-wave region
    float* base = ep + w * 2112;
#pragma unroll
    for (int t = 0; t < 8; t++)
#pragma unroll
        for (int j = 0; j < 4; j++)
            base[(4 * lk + j) * 132 + t * 16 + lrow] = acc[t][j];
    __syncthreads();

    // coalesced write: lane covers row l>>2, cols (l&3)*32..+31
    int row16 = l >> 2, c0 = (l & 3) * 32;
    int orow = rbase + row16;
    if (orow < N) {
        float dn = dinv[orow];
        const float* src = base + row16 * 132 + c0;
        unsigned short* dst = A + (size_t)orow * 128 + c0;
#pragma unroll
        for (int q = 0; q < 4; q++) {
            union { short8 s; unsigned short u[8]; } pk;
#pragma unroll
            for (int e = 0; e < 8; e++) pk.u[e] = f2bf(src[q * 8 + e] * dn);
            *(short8*)(dst + q * 8) = pk.s;
        }
    }
}

// ---------------- Aggregation ----------------
// A rows already carry dinv[src]. B[n] = relu(dinv[n]*(sum_slots A'[src]) + bias), bf16 out.

__global__ __launch_bounds__(256) void k_agg(const unsigned short* __restrict__ A, const int* __restrict__ cnt,
                                             const int* __restrict__ ell, const float* __restrict__ dinv,
                                             const float* __restrict__ bias, unsigned short* __restrict__ Bout, int N) {
    int wid = blockIdx.x * 4 + (threadIdx.x >> 6);
    int lane = threadIdx.x & 63;
    if (wid >= N) return;
    int hi = lane >> 5, li = lane & 31;
    const ushort4* __restrict__ A4 = (const ushort4*)A;
    int deg = cnt[wid];
    float dn = dinv[wid];
    const int* __restrict__ lst = ell + wid * ELL_D;

    int total = deg + 1;          // + virtual self edge at slot==deg
    int pairs = (total + 1) >> 1;

    float4 a0 = {0,0,0,0}, a1 = {0,0,0,0}, a2 = {0,0,0,0}, a3 = {0,0,0,0};
    int i = 0;
    for (; i + 4 <= pairs; i += 4) {
        int s0 = 2 * i + hi, s1 = s0 + 2, s2 = s0 + 4, s3 = s0 + 6;
        int e0 = (s0 < deg) ? lst[s0] : wid;
        int e1 = (s1 < deg) ? lst[s1] : wid;
        int e2 = (s2 < deg) ? lst[s2] : wid;
        int e3 = (s3 < deg) ? lst[s3] : wid;
        float m0 = (s0 < total) ? 1.f : 0.f;
        float m1 = (s1 < total) ? 1.f : 0.f;
        float m2 = (s2 < total) ? 1.f : 0.f;
        float m3 = (s3 < total) ? 1.f : 0.f;
        ushort4 v0 = A4[e0 * 32 + li];
        ushort4 v1 = A4[e1 * 32 + li];
        ushort4 v2 = A4[e2 * 32 + li];
        ushort4 v3 = A4[e3 * 32 + li];
        a0.x = fmaf(bf2f(v0.x), m0, a0.x); a0.y = fmaf(bf2f(v0.y), m0, a0.y);
        a0.z = fmaf(bf2f(v0.z), m0, a0.z); a0.w = fmaf(bf2f(v0.w), m0, a0.w);
        a1.x = fmaf(bf2f(v1.x), m1, a1.x); a1.y = fmaf(bf2f(v1.y), m1, a1.y);
        a1.z = fmaf(bf2f(v1.z), m1, a1.z); a1.w = fmaf(bf2f(v1.w), m1, a1.w);
        a2.x = fmaf(bf2f(v2.x), m2, a2.x); a2.y = fmaf(bf2f(v2.y), m2, a2.y);
        a2.z = fmaf(bf2f(v2.z), m2, a2.z); a2.w = fmaf(bf2f(v2.w), m2, a2.w);
        a3.x = fmaf(bf2f(v3.x), m3, a3.x); a3.y = fmaf(bf2f(v3.y), m3, a3.y);
        a3.z = fmaf(bf2f(v3.z), m3, a3.z); a3.w = fmaf(bf2f(v3.w), m3, a3.w);
    }
    for (; i < pairs; i++) {
        int s0 = 2 * i + hi;
        int e0 = (s0 < deg) ? lst[s0] : wid;
        float m0 = (s0 < total) ? 1.f : 0.f;
        ushort4 v0 = A4[e0 * 32 + li];
        a0.x = fmaf(bf2f(v0.x), m0, a0.x); a0.y = fmaf(bf2f(v0.y), m0, a0.y);
        a0.z = fmaf(bf2f(v0.z), m0, a0.z); a0.w = fmaf(bf2f(v0.w), m0, a0.w);
    }
    a0.x = (a0.x + a1.x) + (a2.x + a3.x);
    a0.y = (a0.y + a1.y) + (a2.y + a3.y);
    a0.z = (a0.z + a1.z) + (a2.z + a3.z);
    a0.w = (a0.w + a1.w) + (a2.w + a3.w);
    a0.x += __shfl_xor(a0.x, 32, 64);
    a0.y += __shfl_xor(a0.y, 32, 64);
    a0.z += __shfl_xor(a0.z, 32, 64);
    a0.w += __shfl_xor(a0.w, 32, 64);

    if (hi == 0) {
        const float4* __restrict__ b4 = (const float4*)bias;
        float4 bb = b4[li];
        ushort4 o;
        o.x = f2bf(fmaxf(fmaf(a0.x, dn, bb.x), 0.f));
        o.y = f2bf(fmaxf(fmaf(a0.y, dn, bb.y), 0.f));
        o.z = f2bf(fmaxf(fmaf(a0.z, dn, bb.z), 0.f));
        o.w = f2bf(fmaxf(fmaf(a0.w, dn, bb.w), 0.f));
        ((ushort4*)Bout)[wid * 32 + li] = o;
    }
}

// ---------------- Pool (mean per graph, sorted batch) + head; B is bf16 ----------------

__global__ __launch_bounds__(512) void k_pool(const unsigned short* __restrict__ B, const int* __restrict__ batch,
                                              const float* __restrict__ Wl, const float* __restrict__ bl,
                                              float* __restrict__ out, int N) {
    int g = blockIdx.x;
    int tid = threadIdx.x;
    int k = tid & 127, h = tid >> 7;  // h in 0..3
    __shared__ int se[2];
    __shared__ float red[4][128];
    if (tid < 2) {
        int target = g + tid;  // lower_bound(batch, target)
        int lo = 0, hi = N;
        while (lo < hi) {
            int mid = (lo + hi) >> 1;
            if (batch[mid] < target) lo = mid + 1; else hi = mid;
        }
        se[tid] = lo;
    }
    __syncthreads();
    int start = se[0], end = se[1];
    float s = 0.f;
    for (int n = start + h; n < end; n += 4) s += bf2f(B[n * 128 + k]);
    red[h][k] = s;
    __syncthreads();
    if (h == 0) {
        float tot = red[0][k] + red[1][k] + red[2][k] + red[3][k];
        int cg = end - start;
        red[0][k] = tot / (float)(cg > 1 ? cg : 1);
    }
    __syncthreads();
    if (tid < 10) {
        float o = bl[tid];
        for (int j = 0; j < 128; j++) o = fmaf(red[0][j], Wl[j * 10 + tid], o);
        out[g * 10 + tid] = o;
    }
}

// ---------------- launch ----------------

extern "C" void kernel_launch(void* const* d_in, const int* in_sizes, int n_in,
                              void* d_out, int out_size, void* d_ws, size_t ws_size,
                              hipStream_t stream) {
    const float* x  = (const float*)d_in[0];
    const int* eidx = (const int*)d_in[1];
    const int* batch = (const int*)d_in[2];
    const float* W0 = (const float*)d_in[3];
    const float* b0 = (const float*)d_in[4];
    const float* W1 = (const float*)d_in[5];
    const float* b1 = (const float*)d_in[6];
    const float* W2 = (const float*)d_in[7];
    const float* b2 = (const float*)d_in[8];
    const float* Wl = (const float*)d_in[9];
    const float* bl = (const float*)d_in[10];

    int N = in_sizes[0] / 128;
    int E = in_sizes[1] / 2;
    int G = out_size / 10;
    const int* row = eidx;      // edge_index[0] = source
    const int* col = eidx + E;  // edge_index[1] = target

    char* w = (char*)d_ws;
    auto carve = [&](size_t bytes) -> void* {
        void* p = (void*)w;
        w += (bytes + 511) & ~(size_t)511;
        return p;
    };
    unsigned short* A  = (unsigned short*)carve((size_t)N * 128 * 2);  // bf16
    unsigned short* Bb = (unsigned short*)carve((size_t)N * 128 * 2);  // bf16
    int*   cnt  = (int*)carve((size_t)N * 4);
    float* dinv = (float*)carve((size_t)N * 4);
    int*   ell  = (int*)carve((size_t)N * ELL_D * 4);
    unsigned short* WT1 = (unsigned short*)carve(16384 * 2);
    unsigned short* WT2 = (unsigned short*)carve(16384 * 2);

    int gb = (N + 63) / 64;
    int ft = (E + 3) / 4;
    int fb = (ft + 255) / 256;
    int M  = (gb > fb) ? gb : fb;

    hipMemsetAsync(cnt, 0, (size_t)N * 4, stream);
    k_prep_wt<<<2, 256, 0, stream>>>(W1, W2, WT1, WT2);
    // layer-1 gemm (f32 vector) overlapped with ELL build
    k_fused_gemm_fill<<<2 * M, 256, 0, stream>>>(x, W0, A, col, row, cnt, ell, N, E, gb, fb);
    k_dinv_scaleA<<<(N + 7) / 8, 256, 0, stream>>>(cnt, dinv, A, N);

    int ab = (N + 3) / 4;
    int mb = (N + 63) / 64;
    k_agg<<<ab, 256, 0, stream>>>(A, cnt, ell, dinv, b0, Bb, N);
    // layer 2
    k_gemm_mfma<<<mb, 256, 0, stream>>>(Bb, WT1, dinv, A, N);
    k_agg<<<ab, 256, 0, stream>>>(A, cnt, ell, dinv, b1, Bb, N);
    // layer 3
    k_gemm_mfma<<<mb, 256, 0, stream>>>(Bb, WT2, dinv, A, N);
    k_agg<<<ab, 256, 0, stream>>>(A, cnt, ell, dinv, b2, Bb, N);
    // pool + head
    k_pool<<<G, 512, 0, stream>>>(Bb, batch, Wl, bl, (float*)d_out, N);
}